// Round 2
// baseline (1376.668 us; speedup 1.0000x reference)
//
#include <hip/hip_runtime.h>
#include <math.h>

#define B_SZ 4096
#define N_SZ 200
#define K_SZ 64
#define H1 80
#define H2 40
#define NEG_V (-4294967295.0f)

// ---------------- Phase 0a: qW[b][h] = b1[h] + sum_i q[b][i]*(W1[i][h]+W1[128+i][h])
__global__ __launch_bounds__(128) void qw_kernel(const float* __restrict__ query,
                                                 const float* __restrict__ W1,
                                                 const float* __restrict__ b1,
                                                 float* __restrict__ qW) {
    int b = blockIdx.x;
    int tid = threadIdx.x;
    __shared__ float sq[K_SZ];
    if (tid < K_SZ) sq[tid] = query[b * K_SZ + tid];
    __syncthreads();
    if (tid < H1) {
        float acc = b1[tid];
#pragma unroll 8
        for (int i = 0; i < K_SZ; ++i) {
            acc += sq[i] * (W1[i * H1 + tid] + W1[(128 + i) * H1 + tid]);
        }
        qW[b * H1 + tid] = acc;
    }
}

// ---------------- Phase 0b: combined layer-1 weights, contiguous per il:
// Wc[il][0..79]  = W1[64+il][h] - W1[128+il][h]   (k coefficient)
// Wc[il][80..159]= W1[192+il][h]                  (q*k coefficient)
__global__ __launch_bounds__(256) void prep_wc(const float* __restrict__ W1,
                                               float* __restrict__ Wc) {
    int idx = blockIdx.x * 256 + threadIdx.x;
    if (idx >= K_SZ * 2 * H1) return;
    int il = idx / (2 * H1);
    int r = idx % (2 * H1);
    float v;
    if (r < H1) v = W1[(64 + il) * H1 + r] - W1[(128 + il) * H1 + r];
    else        v = W1[(192 + il) * H1 + (r - H1)];
    Wc[il * (2 * H1) + r] = v;
}

// ---------------- Phase 1: per-(b,n) score. Weights via wave-uniform (scalar)
// loads; only per-lane k data goes through LDS.
__global__ __launch_bounds__(256) void score_kernel(
    const float* __restrict__ query, const float* __restrict__ key,
    const int* __restrict__ mask,
    const float* __restrict__ Wc, const float* __restrict__ a1,
    const float* __restrict__ W2, const float* __restrict__ b2,
    const float* __restrict__ a2,
    const float* __restrict__ Wo, const float* __restrict__ bo,
    const float* __restrict__ qW, float* __restrict__ scores) {
    __shared__ float skc[16 * 257];     // k chunk [il][thread], padded (bank-safe)
    __shared__ float sq[3 * K_SZ];      // up to 3 distinct b rows per block

    const int tid = threadIdx.x;
    const int p0 = blockIdx.x * 256;
    const int p  = p0 + tid;            // pair index (grid exact)
    const int b  = p / N_SZ;
    const int bfirst = p0 / N_SZ;
    const int lb = b - bfirst;          // 0..2

    for (int idx = tid; idx < 3 * K_SZ; idx += 256) {
        int bb = bfirst + idx / K_SZ;
        sq[idx] = (bb < B_SZ) ? query[bb * K_SZ + (idx & 63)] : 0.0f;
    }

    // ---- init accumulator from per-b part (L1-broadcast global float4 loads)
    float acc1[H1];
    {
        const float4* qW4 = reinterpret_cast<const float4*>(qW + (size_t)b * H1);
#pragma unroll
        for (int h4 = 0; h4 < H1 / 4; ++h4) {
            float4 v = qW4[h4];
            acc1[h4 * 4 + 0] = v.x;
            acc1[h4 * 4 + 1] = v.y;
            acc1[h4 * 4 + 2] = v.z;
            acc1[h4 * 4 + 3] = v.w;
        }
    }

    // ---- layer 1 over i-chunks of 16
    for (int c = 0; c < K_SZ; c += 16) {
        __syncthreads();  // protect previous chunk
#pragma unroll
        for (int r = 0; r < 4; ++r) {
            int idx = r * 256 + tid;        // 0..1023
            int trow = idx >> 2;            // 0..255
            int il4 = (idx & 3) * 4;        // 0,4,8,12
            float4 v = *reinterpret_cast<const float4*>(
                &key[(size_t)(p0 + trow) * K_SZ + c + il4]);
            skc[(il4 + 0) * 257 + trow] = v.x;
            skc[(il4 + 1) * 257 + trow] = v.y;
            skc[(il4 + 2) * 257 + trow] = v.z;
            skc[(il4 + 3) * 257 + trow] = v.w;
        }
        __syncthreads();
#pragma unroll 2
        for (int il = 0; il < 16; ++il) {
            float kk = skc[il * 257 + tid];
            float qq = sq[lb * K_SZ + c + il];
            float pp = qq * kk;
            const float* __restrict__ w = &Wc[(c + il) * (2 * H1)];
#pragma unroll
            for (int h = 0; h < H1; ++h) {
                acc1[h] += kk * w[h] + pp * w[H1 + h];
            }
        }
    }

    // ---- layer 2 (fully unrolled; weights wave-uniform -> scalar pipe)
    float acc2[H2];
#pragma unroll
    for (int m = 0; m < H2; ++m) acc2[m] = b2[m];
#pragma unroll
    for (int j = 0; j < H1; ++j) {
        float h = acc1[j];
        float hv = (h > 0.0f) ? h : a1[j] * h;
#pragma unroll
        for (int m = 0; m < H2; ++m) acc2[m] += hv * W2[j * H2 + m];
    }

    // ---- output layer + mask
    float sc = bo[0];
#pragma unroll
    for (int m = 0; m < H2; ++m) {
        float h = acc2[m];
        float hv = (h > 0.0f) ? h : a2[m] * h;
        sc += hv * Wo[m];
    }
    int mv = mask[p];
    scores[p] = (mv == 0) ? NEG_V : sc;
}

// ---------------- Phase 3: softmax over N + weighted value sum
__global__ __launch_bounds__(256) void softmax_out_kernel(
    const float* __restrict__ scores, const float* __restrict__ value,
    float* __restrict__ out) {
    int b = blockIdx.x;
    int tid = threadIdx.x;
    __shared__ float sprob[256];
    __shared__ float sred[8];
    __shared__ float spart[4 * K_SZ];

    float s = (tid < N_SZ) ? scores[b * N_SZ + tid] : -INFINITY;
    float m = s;
#pragma unroll
    for (int off = 32; off >= 1; off >>= 1) m = fmaxf(m, __shfl_xor(m, off));
    if ((tid & 63) == 0) sred[tid >> 6] = m;
    __syncthreads();
    m = fmaxf(fmaxf(sred[0], sred[1]), fmaxf(sred[2], sred[3]));

    float e = (tid < N_SZ) ? expf(s - m) : 0.0f;
    sprob[tid] = e;
    float t = e;
#pragma unroll
    for (int off = 32; off >= 1; off >>= 1) t += __shfl_xor(t, off);
    if ((tid & 63) == 0) sred[4 + (tid >> 6)] = t;
    __syncthreads();
    float inv = 1.0f / (sred[4] + sred[5] + sred[6] + sred[7]);

    int w = tid >> 6;
    int l = tid & 63;
    float acc0 = 0.0f, acc1v = 0.0f;
#pragma unroll 5
    for (int jj = 0; jj < 50; jj += 2) {
        int n = w * 50 + jj;
        acc0  += sprob[n]     * value[((size_t)b * N_SZ + n)     * K_SZ + l];
        acc1v += sprob[n + 1] * value[((size_t)b * N_SZ + n + 1) * K_SZ + l];
    }
    spart[w * K_SZ + l] = acc0 + acc1v;
    __syncthreads();
    if (tid < K_SZ) {
        out[b * K_SZ + tid] =
            (spart[tid] + spart[64 + tid] + spart[128 + tid] + spart[192 + tid]) * inv;
    }
}

extern "C" void kernel_launch(void* const* d_in, const int* in_sizes, int n_in,
                              void* d_out, int out_size, void* d_ws, size_t ws_size,
                              hipStream_t stream) {
    const float* query = (const float*)d_in[0];
    const float* key   = (const float*)d_in[1];
    const float* value = (const float*)d_in[2];
    const int*   mask  = (const int*)d_in[3];
    const float* W1    = (const float*)d_in[4];
    const float* b1    = (const float*)d_in[5];
    const float* a1    = (const float*)d_in[6];
    const float* W2    = (const float*)d_in[7];
    const float* b2    = (const float*)d_in[8];
    const float* a2    = (const float*)d_in[9];
    const float* Wo    = (const float*)d_in[10];
    const float* bo    = (const float*)d_in[11];
    float* out = (float*)d_out;

    float* qW     = (float*)d_ws;                    // B*H1 floats
    float* scores = qW + (size_t)B_SZ * H1;          // B*N floats
    float* Wc     = scores + (size_t)B_SZ * N_SZ;    // 64*160 floats

    qw_kernel<<<B_SZ, 128, 0, stream>>>(query, W1, b1, qW);
    prep_wc<<<(K_SZ * 2 * H1 + 255) / 256, 256, 0, stream>>>(W1, Wc);
    score_kernel<<<(B_SZ * N_SZ) / 256, 256, 0, stream>>>(
        query, key, mask, Wc, a1, W2, b2, a2, Wo, bo, qW, scores);
    softmax_out_kernel<<<B_SZ, 256, 0, stream>>>(scores, value, out);
}

// Round 3
// 169.402 us; speedup vs baseline: 8.1267x; 8.1267x over previous
//
#include <hip/hip_runtime.h>
#include <math.h>

#define B_SZ 4096
#define N_SZ 200
#define K_SZ 64
#define H1 80
#define H2 40
#define NEG_V (-4294967295.0f)

#define ROWS 128
#define A2S 104   // A2 row stride in halves: 208B = 13*16 (aligned, 2-way-free)

typedef _Float16 f16x8 __attribute__((ext_vector_type(8)));
typedef _Float16 f16x4 __attribute__((ext_vector_type(4)));
typedef float f32x4 __attribute__((ext_vector_type(4)));

// ---------------- qW[b][h] = b1[h] + sum_i q[b][i]*(W1[i][h]+W1[128+i][h])  (exact fp32)
__global__ __launch_bounds__(128) void qw_kernel(const float* __restrict__ query,
                                                 const float* __restrict__ W1,
                                                 const float* __restrict__ b1,
                                                 float* __restrict__ qW) {
    int b = blockIdx.x;
    int tid = threadIdx.x;
    __shared__ float sq[K_SZ];
    if (tid < K_SZ) sq[tid] = query[b * K_SZ + tid];
    __syncthreads();
    if (tid < H1) {
        float acc = b1[tid];
#pragma unroll 8
        for (int i = 0; i < K_SZ; ++i)
            acc += sq[i] * (W1[i * H1 + tid] + W1[(128 + i) * H1 + tid]);
        qW[b * H1 + tid] = acc;
    }
}

// ---------------- pack layer-1/2 weights into MFMA B-fragment order, hi/lo fp16 split
// B-frag (16x16x32): lane l, elem j holds B[k = ks*32 + (l>>4)*8 + j][col = l&15]
__global__ __launch_bounds__(256) void prep_bp(const float* __restrict__ W1,
                                               const float* __restrict__ W2,
                                               _Float16* __restrict__ Bp1h, _Float16* __restrict__ Bp1l,
                                               _Float16* __restrict__ Bp2h, _Float16* __restrict__ Bp2l) {
    int idx = blockIdx.x * 256 + threadIdx.x;
    if (idx < 5 * 4 * 64 * 8) {                 // layer1: 5 ht * 4 ks
        int j = idx & 7, lane = (idx >> 3) & 63, f = idx >> 9;  // f = ht*4+ks
        int ks = f & 3, ht = f >> 2;
        int k = ks * 32 + (lane >> 4) * 8 + j;  // 0..127: 0-63 = k-coef, 64-127 = q*k-coef
        int h = ht * 16 + (lane & 15);
        float w = (k < 64) ? (W1[(64 + k) * H1 + h] - W1[(128 + k) * H1 + h])
                           : W1[(192 + (k - 64)) * H1 + h];
        _Float16 hi = (_Float16)w;
        Bp1h[idx] = hi;
        Bp1l[idx] = (_Float16)(w - (float)hi);
    } else {
        int idx2 = idx - 5 * 4 * 64 * 8;
        if (idx2 < 9 * 64 * 8) {                // layer2: 3 ht2 * 3 ks2 (K 80->96, N 40->48 zero-pad)
            int j = idx2 & 7, lane = (idx2 >> 3) & 63, f = idx2 >> 9;  // f = ht2*3+ks2
            int ks2 = f % 3, ht2 = f / 3;
            int k2 = ks2 * 32 + (lane >> 4) * 8 + j;
            int m = ht2 * 16 + (lane & 15);
            float w = (k2 < H1 && m < H2) ? W2[k2 * H2 + m] : 0.0f;
            _Float16 hi = (_Float16)w;
            Bp2h[idx2] = hi;
            Bp2l[idx2] = (_Float16)(w - (float)hi);
        }
    }
}

// ---------------- fused MFMA score kernel: 128 rows/block, 4 waves x 2 m-tiles
__global__ __launch_bounds__(256) void score_mfma(
    const float* __restrict__ query, const float* __restrict__ key,
    const int* __restrict__ mask,
    const _Float16* __restrict__ Bp1h, const _Float16* __restrict__ Bp1l,
    const _Float16* __restrict__ Bp2h, const _Float16* __restrict__ Bp2l,
    const float* __restrict__ a1, const float* __restrict__ b2,
    const float* __restrict__ a2, const float* __restrict__ Wo,
    const float* __restrict__ bo,
    const float* __restrict__ qW, float* __restrict__ scores) {
    __shared__ _Float16 smemA[ROWS * 128];   // A1 [128][128] (XOR-swizzled) -> reused as A2 [128][A2S]
    __shared__ float sq[2 * K_SZ];
    __shared__ float sqW[2 * H1];
    __shared__ float sa1[H1];
    __shared__ float sb2[48], sa2[48], sWo[48];
    __shared__ float ssc[ROWS];

    const int tid = threadIdx.x;
    const int wv = tid >> 6;
    const int l = tid & 63;
    const int l15 = l & 15;
    const int lg = l >> 4;
    const int p0 = blockIdx.x * ROWS;
    const int bfirst = p0 / N_SZ;
    const int bsplit = (bfirst + 1) * N_SZ - p0;  // local row where b increments (>=128 if none)

    // ---- stage params
    for (int i = tid; i < 2 * K_SZ; i += 256) {
        int bb = bfirst + (i >> 6);
        sq[i] = (bb < B_SZ) ? query[bb * K_SZ + (i & 63)] : 0.0f;
    }
    for (int i = tid; i < 2 * H1; i += 256) {
        int sec = (i >= H1) ? 1 : 0;
        int bb = bfirst + sec;
        sqW[i] = (bb < B_SZ) ? qW[bb * H1 + (i - sec * H1)] : 0.0f;
    }
    for (int i = tid; i < H1; i += 256) sa1[i] = a1[i];
    for (int i = tid; i < 48; i += 256) {
        sb2[i] = (i < H2) ? b2[i] : 0.0f;
        sa2[i] = (i < H2) ? a2[i] : 0.0f;
        sWo[i] = (i < H2) ? Wo[i] : 0.0f;
    }
    __syncthreads();

    // ---- stage A1 features: [row][i] fp16, i<64 = k, i>=64 = q*k; XOR-swizzled
#pragma unroll
    for (int r = 0; r < 8; ++r) {
        int idx = r * 256 + tid;          // 0..2047
        int trow = idx >> 4;
        int c4 = idx & 15;
        float4 kv = *reinterpret_cast<const float4*>(&key[((size_t)(p0 + trow)) * K_SZ + c4 * 4]);
        int lb = (trow >= bsplit) ? 1 : 0;
        float4 qv = *reinterpret_cast<const float4*>(&sq[lb * K_SZ + c4 * 4]);
        int base = trow * 128 + c4 * 4;
        int sw = (trow & 7) << 3;         // XOR in 8-half (16B) units
        f16x4 kk, qk;
        kk[0] = (_Float16)kv.x; kk[1] = (_Float16)kv.y; kk[2] = (_Float16)kv.z; kk[3] = (_Float16)kv.w;
        qk[0] = (_Float16)(qv.x * kv.x); qk[1] = (_Float16)(qv.y * kv.y);
        qk[2] = (_Float16)(qv.z * kv.z); qk[3] = (_Float16)(qv.w * kv.w);
        *reinterpret_cast<f16x4*>(&smemA[base ^ sw]) = kk;
        *reinterpret_cast<f16x4*>(&smemA[(base + 64) ^ sw]) = qk;
    }
    __syncthreads();

    // ---- layer 1: C1[128 x 80] = A1[128 x 128] @ B1[128 x 80], B hi/lo split
    f32x4 acc[2][5];
#pragma unroll
    for (int mt = 0; mt < 2; ++mt)
#pragma unroll
        for (int ht = 0; ht < 5; ++ht) acc[mt][ht] = (f32x4){0.f, 0.f, 0.f, 0.f};

#pragma unroll
    for (int ks = 0; ks < 4; ++ks) {
        f16x8 af[2];
#pragma unroll
        for (int mt = 0; mt < 2; ++mt) {
            int row = (wv * 2 + mt) * 16 + l15;
            int hidx = (row * 128 + ks * 32 + lg * 8) ^ ((row & 7) << 3);
            af[mt] = *reinterpret_cast<const f16x8*>(&smemA[hidx]);
        }
#pragma unroll
        for (int ht = 0; ht < 5; ++ht) {
            int bidx = ((ht * 4 + ks) * 64 + l) * 8;
            f16x8 bh = *reinterpret_cast<const f16x8*>(&Bp1h[bidx]);
            f16x8 bl = *reinterpret_cast<const f16x8*>(&Bp1l[bidx]);
#pragma unroll
            for (int mt = 0; mt < 2; ++mt) {
                acc[mt][ht] = __builtin_amdgcn_mfma_f32_16x16x32_f16(af[mt], bh, acc[mt][ht], 0, 0, 0);
                acc[mt][ht] = __builtin_amdgcn_mfma_f32_16x16x32_f16(af[mt], bl, acc[mt][ht], 0, 0, 0);
            }
        }
    }
    __syncthreads();   // all A1 reads complete before overwriting as A2

    // ---- epilogue 1: h1 = prelu(C1 + qW) -> A2 [row][h] fp16, stride A2S
    _Float16* A2 = smemA;
#pragma unroll
    for (int mt = 0; mt < 2; ++mt) {
#pragma unroll
        for (int ht = 0; ht < 5; ++ht) {
            int h = ht * 16 + l15;
            float aa = sa1[h];
#pragma unroll
            for (int j = 0; j < 4; ++j) {
                int n = (wv * 2 + mt) * 16 + lg * 4 + j;
                int lb = (n >= bsplit) ? 1 : 0;
                float v = acc[mt][ht][j] + sqW[lb * H1 + h];
                float pre = (v > 0.0f) ? v : v * aa;
                A2[n * A2S + h] = (_Float16)pre;
            }
        }
    }
    // zero-pad A2 cols 80..95 (read by ks2=2)
#pragma unroll
    for (int z = 0; z < 2; ++z) {
        int unit = z * 256 + tid;  // 0..511
        int row = unit >> 2, qd = unit & 3;
        f16x4 zz = {(_Float16)0, (_Float16)0, (_Float16)0, (_Float16)0};
        *reinterpret_cast<f16x4*>(&A2[row * A2S + 80 + qd * 4]) = zz;
    }
    __syncthreads();

    // ---- layer 2: C2[128 x 48] = A2[128 x 96] @ B2[96 x 48], B hi/lo split
    f32x4 acc2[2][3];
#pragma unroll
    for (int mt = 0; mt < 2; ++mt)
#pragma unroll
        for (int ht = 0; ht < 3; ++ht) acc2[mt][ht] = (f32x4){0.f, 0.f, 0.f, 0.f};

#pragma unroll
    for (int ks = 0; ks < 3; ++ks) {
        f16x8 a2f[2];
#pragma unroll
        for (int mt = 0; mt < 2; ++mt) {
            int row = (wv * 2 + mt) * 16 + l15;
            a2f[mt] = *reinterpret_cast<const f16x8*>(&A2[row * A2S + ks * 32 + lg * 8]);
        }
#pragma unroll
        for (int ht = 0; ht < 3; ++ht) {
            int bidx = ((ht * 3 + ks) * 64 + l) * 8;
            f16x8 bh = *reinterpret_cast<const f16x8*>(&Bp2h[bidx]);
            f16x8 bl = *reinterpret_cast<const f16x8*>(&Bp2l[bidx]);
#pragma unroll
            for (int mt = 0; mt < 2; ++mt) {
                acc2[mt][ht] = __builtin_amdgcn_mfma_f32_16x16x32_f16(a2f[mt], bh, acc2[mt][ht], 0, 0, 0);
                acc2[mt][ht] = __builtin_amdgcn_mfma_f32_16x16x32_f16(a2f[mt], bl, acc2[mt][ht], 0, 0, 0);
            }
        }
    }

    // ---- epilogue 2 + layer 3: score = Wo . prelu(C2 + b2), 16-lane shfl reduce
    float bov = bo[0];
#pragma unroll
    for (int mt = 0; mt < 2; ++mt) {
#pragma unroll
        for (int j = 0; j < 4; ++j) {
            float psum = 0.0f;
#pragma unroll
            for (int ht = 0; ht < 3; ++ht) {
                int m = ht * 16 + l15;
                float v = acc2[mt][ht][j] + sb2[m];
                float pre = (v > 0.0f) ? v : v * sa2[m];
                psum += pre * sWo[m];   // sWo[m>=40] = 0
            }
            psum += __shfl_xor(psum, 1);
            psum += __shfl_xor(psum, 2);
            psum += __shfl_xor(psum, 4);
            psum += __shfl_xor(psum, 8);
            if (l15 == 0) ssc[(wv * 2 + mt) * 16 + lg * 4 + j] = psum;
        }
    }
    __syncthreads();
    if (tid < ROWS) {
        int p = p0 + tid;
        float sc = ssc[tid] + bov;
        scores[p] = (mask[p] == 0) ? NEG_V : sc;
    }
}

// ---------------- softmax over N + weighted value sum
__global__ __launch_bounds__(256) void softmax_out_kernel(
    const float* __restrict__ scores, const float* __restrict__ value,
    float* __restrict__ out) {
    int b = blockIdx.x;
    int tid = threadIdx.x;
    __shared__ float sprob[256];
    __shared__ float sred[8];
    __shared__ float spart[4 * K_SZ];

    float s = (tid < N_SZ) ? scores[b * N_SZ + tid] : -INFINITY;
    float m = s;
#pragma unroll
    for (int off = 32; off >= 1; off >>= 1) m = fmaxf(m, __shfl_xor(m, off));
    if ((tid & 63) == 0) sred[tid >> 6] = m;
    __syncthreads();
    m = fmaxf(fmaxf(sred[0], sred[1]), fmaxf(sred[2], sred[3]));

    float e = (tid < N_SZ) ? expf(s - m) : 0.0f;
    sprob[tid] = e;
    float t = e;
#pragma unroll
    for (int off = 32; off >= 1; off >>= 1) t += __shfl_xor(t, off);
    if ((tid & 63) == 0) sred[4 + (tid >> 6)] = t;
    __syncthreads();
    float inv = 1.0f / (sred[4] + sred[5] + sred[6] + sred[7]);

    int w = tid >> 6;
    int l = tid & 63;
    float acc0 = 0.0f, acc1v = 0.0f;
#pragma unroll 5
    for (int jj = 0; jj < 50; jj += 2) {
        int n = w * 50 + jj;
        acc0  += sprob[n]     * value[((size_t)b * N_SZ + n)     * K_SZ + l];
        acc1v += sprob[n + 1] * value[((size_t)b * N_SZ + n + 1) * K_SZ + l];
    }
    spart[w * K_SZ + l] = acc0 + acc1v;
    __syncthreads();
    if (tid < K_SZ) {
        out[b * K_SZ + tid] =
            (spart[tid] + spart[64 + tid] + spart[128 + tid] + spart[192 + tid]) * inv;
    }
}

extern "C" void kernel_launch(void* const* d_in, const int* in_sizes, int n_in,
                              void* d_out, int out_size, void* d_ws, size_t ws_size,
                              hipStream_t stream) {
    const float* query = (const float*)d_in[0];
    const float* key   = (const float*)d_in[1];
    const float* value = (const float*)d_in[2];
    const int*   mask  = (const int*)d_in[3];
    const float* W1    = (const float*)d_in[4];
    const float* b1    = (const float*)d_in[5];
    const float* a1    = (const float*)d_in[6];
    const float* W2    = (const float*)d_in[7];
    const float* b2    = (const float*)d_in[8];
    const float* a2    = (const float*)d_in[9];
    const float* Wo    = (const float*)d_in[10];
    const float* bo    = (const float*)d_in[11];
    float* out = (float*)d_out;

    float* qW     = (float*)d_ws;                        // B*H1 floats
    float* scores = qW + (size_t)B_SZ * H1;              // B*N floats
    _Float16* Bp1h = (_Float16*)(scores + (size_t)B_SZ * N_SZ);  // 10240 halves (16B-aligned)
    _Float16* Bp1l = Bp1h + 5 * 4 * 64 * 8;
    _Float16* Bp2h = Bp1l + 5 * 4 * 64 * 8;              // 4608 halves
    _Float16* Bp2l = Bp2h + 9 * 64 * 8;

    qw_kernel<<<B_SZ, 128, 0, stream>>>(query, W1, b1, qW);
    prep_bp<<<58, 256, 0, stream>>>(W1, W2, Bp1h, Bp1l, Bp2h, Bp2l);
    score_mfma<<<(B_SZ * N_SZ) / ROWS, 256, 0, stream>>>(
        query, key, mask, Bp1h, Bp1l, Bp2h, Bp2l, a1, b2, a2, Wo, bo, qW, scores);
    softmax_out_kernel<<<B_SZ, 256, 0, stream>>>(scores, value, out);
}